// Round 8
// baseline (343.368 us; speedup 1.0000x reference)
//
#include <hip/hip_runtime.h>

#define N_NODES 50000
#define N_EDGES 800000
#define DIM     256
#define NSTRIPS 1563          // ceil(50000/32); 1563*32 = 50016
#define GRID    256           // == CU count; 1 block/CU (128 KB LDS) -> all resident
#define NT      512
#define NWAVES  (GRID * 8)    // 2048
#define CNT_THREADS ((NWAVES - NSTRIPS) * 64)   // 485 waves * 64 = 31040
#define NBLK_NODES 196        // ceil(50000/256)

typedef __attribute__((ext_vector_type(8))) short bf16x8;
typedef __attribute__((ext_vector_type(4))) float f32x4;

__device__ __forceinline__ unsigned short f2bf(float f) {
    unsigned u = __float_as_uint(f);
    unsigned r = (u + 0x7fffu + ((u >> 16) & 1u)) >> 16;
    return (unsigned short)r;
}
__device__ __forceinline__ float bf2f(unsigned short h) {
    return __uint_as_float((unsigned)h << 16);
}

// device-scope grid barrier; monotonically increasing counter, target = phase*GRID.
// Safe: grid == 256 blocks, 1 block/CU (LDS-bound) -> all blocks resident.
__device__ __forceinline__ void gridbar(unsigned* bar, unsigned target) {
    __syncthreads();
    if (threadIdx.x == 0) {
        __threadfence();                               // release prior writes (device scope)
        atomicAdd(bar, 1u);
        while (__hip_atomic_load(bar, __ATOMIC_RELAXED, __HIP_MEMORY_SCOPE_AGENT) < target)
            __builtin_amdgcn_s_sleep(2);
        __threadfence();                               // acquire
    }
    __syncthreads();
}

// exclusive scan over 512 values (8 waves of 64)
__device__ __forceinline__ int excl_scan_512(int v, int* wsum, int* totalp) {
    const int lane = threadIdx.x & 63;
    const int wave = threadIdx.x >> 6;
    int x = v;
#pragma unroll
    for (int off = 1; off < 64; off <<= 1) {
        const int y = __shfl_up(x, off, 64);
        if (lane >= off) x += y;
    }
    if (lane == 63) wsum[wave] = x;
    __syncthreads();
    if (threadIdx.x == 0) {
        int s = 0;
#pragma unroll
        for (int w = 0; w < 8; ++w) { const int t = wsum[w]; wsum[w] = s; s += t; }
        *totalp = s;
    }
    __syncthreads();
    return wsum[wave] + x - v;
}

__global__ __launch_bounds__(NT, 2)
void fused(const float* __restrict__ X, const float* __restrict__ W,
           const int* __restrict__ rows, const int* __restrict__ cols,
           const float* __restrict__ vals, const float* __restrict__ bias,
           unsigned short* __restrict__ Hb, int* __restrict__ offs,
           int* __restrict__ cnt, unsigned* __restrict__ bar,
           int* __restrict__ bsum, unsigned short* __restrict__ rank,
           int2* __restrict__ pe, float* __restrict__ out) {
    __shared__ union {
        unsigned short wl[DIM * DIM];   // 128 KB swizzled W^T (phase 1)
        int P[256];                     // top-level prefix (phases 3-4)
    } sh;
    __shared__ int s_wsum[8];
    __shared__ int s_total;

    const int tid  = threadIdx.x;
    const int bid  = blockIdx.x;
    const int lane = tid & 63;
    const int wid  = tid >> 6;
    const int gw   = bid * 8 + wid;      // global wave id 0..2047

    // =============== Phase 1: (W->LDS transpose; GEMM) || count+rank ===============
    if (bid < NBLK_NODES) {
        // transpose/convert W[k][n] -> sh.wl row n, byte (2k)^((n&7)<<4)
        const int n = tid >> 1;
        const int khalf = tid & 1;
#pragma unroll
        for (int j8 = 0; j8 < 16; ++j8) {
            const int k0 = khalf * 128 + j8 * 8;
            bf16x8 v;
#pragma unroll
            for (int i = 0; i < 8; ++i)
                v[i] = (short)f2bf(W[(size_t)(k0 + i) * DIM + n]);
            const int byteoff = n * 512 + ((k0 * 2) ^ ((n & 7) << 4));
            *(bf16x8*)((char*)sh.wl + byteoff) = v;
        }
        __syncthreads();
    }

    if (gw < NSTRIPS) {
        // ---- GEMM wave: one 32-row strip ----
        const int r0   = gw * 32;
        const int arow = lane & 15;
        const int kgrp = lane >> 4;
        const int ra = r0 + arow;
        const int rb = r0 + 16 + arow;
        const float* xa = X + (size_t)(ra < N_NODES ? ra : N_NODES - 1) * DIM + kgrp * 8;
        const float* xb = X + (size_t)(rb < N_NODES ? rb : N_NODES - 1) * DIM + kgrp * 8;

        f32x4 acc[2][16];
#pragma unroll
        for (int h = 0; h < 2; ++h)
#pragma unroll
            for (int nt = 0; nt < 16; ++nt) acc[h][nt] = f32x4{0.f, 0.f, 0.f, 0.f};

        const int swz = (arow & 7) << 4;
        float4 pa0 = *(const float4*)(xa);
        float4 pa1 = *(const float4*)(xa + 4);
        float4 pb0 = *(const float4*)(xb);
        float4 pb1 = *(const float4*)(xb + 4);

#pragma unroll
        for (int ks = 0; ks < 8; ++ks) {
            bf16x8 a0, a1;
            a0[0] = (short)f2bf(pa0.x); a0[1] = (short)f2bf(pa0.y);
            a0[2] = (short)f2bf(pa0.z); a0[3] = (short)f2bf(pa0.w);
            a0[4] = (short)f2bf(pa1.x); a0[5] = (short)f2bf(pa1.y);
            a0[6] = (short)f2bf(pa1.z); a0[7] = (short)f2bf(pa1.w);
            a1[0] = (short)f2bf(pb0.x); a1[1] = (short)f2bf(pb0.y);
            a1[2] = (short)f2bf(pb0.z); a1[3] = (short)f2bf(pb0.w);
            a1[4] = (short)f2bf(pb1.x); a1[5] = (short)f2bf(pb1.y);
            a1[6] = (short)f2bf(pb1.z); a1[7] = (short)f2bf(pb1.w);
            if (ks < 7) {
                pa0 = *(const float4*)(xa + (ks + 1) * 32);
                pa1 = *(const float4*)(xa + (ks + 1) * 32 + 4);
                pb0 = *(const float4*)(xb + (ks + 1) * 32);
                pb1 = *(const float4*)(xb + (ks + 1) * 32 + 4);
            }
            const int kb = ((ks * 32 + kgrp * 8) * 2) ^ swz;
#pragma unroll
            for (int nt = 0; nt < 16; ++nt) {
                const int n = nt * 16 + arow;
                const bf16x8 b = *(const bf16x8*)((const char*)sh.wl + n * 512 + kb);
                acc[0][nt] = __builtin_amdgcn_mfma_f32_16x16x32_bf16(a0, b, acc[0][nt], 0, 0, 0);
                acc[1][nt] = __builtin_amdgcn_mfma_f32_16x16x32_bf16(a1, b, acc[1][nt], 0, 0, 0);
            }
        }
#pragma unroll
        for (int h = 0; h < 2; ++h) {
            const int crow0 = r0 + h * 16 + kgrp * 4;
#pragma unroll
            for (int nt = 0; nt < 16; ++nt) {
#pragma unroll
                for (int q = 0; q < 4; ++q) {
                    const int r = crow0 + q;
                    if (r < N_NODES)
                        Hb[(size_t)r * DIM + nt * 16 + arow] = f2bf(acc[h][nt][q]);
                }
            }
        }
    } else {
        // ---- count+rank wave: single atomic pass ----
        const int ct = (gw - NSTRIPS) * 64 + lane;
        for (int e = ct; e < N_EDGES; e += CNT_THREADS) {
            const int r = rows[e];
            rank[e] = (unsigned short)atomicAdd(&cnt[r], 1);
        }
    }
    gridbar(bar, GRID);

    // =============== Phase 2: per-256-chunk exclusive scan ===============
    if (bid < NBLK_NODES) {
        const int idx = bid * 256 + tid;           // tid<256 valid
        const int v = (tid < 256 && idx < N_NODES) ? cnt[idx] : 0;
        const int excl = excl_scan_512(v, s_wsum, &s_total);
        if (tid < 256 && idx < N_NODES) offs[idx] = excl;
        if (tid == 0) bsum[bid] = s_total;
    }
    gridbar(bar, 2 * GRID);

    // =============== Phase 3: top prefix (LDS-resident) + fill dest-CSR ===============
    {
        const int v = (tid < NBLK_NODES) ? bsum[tid] : 0;
        const int excl = excl_scan_512(v, s_wsum, &s_total);
        if (tid < 256) sh.P[tid] = excl;
    }
    __syncthreads();
    for (int e = bid * NT + tid; e < N_EDGES; e += GRID * NT) {
        const int r = rows[e];
        pe[offs[r] + sh.P[r >> 8] + (int)rank[e]] =
            make_int2(cols[e], __float_as_int(vals[e]));
    }
    gridbar(bar, 3 * GRID);

    // =============== Phase 4: SpMM out[r] = sum val * hidden[col] + b ===============
    {
        const unsigned lb = (unsigned)lane * 4;
        const float4 bb = *(const float4*)&bias[lane * 4];
        for (int r = gw; r < N_NODES; r += NWAVES) {
            const int beg = offs[r] + sh.P[r >> 8];
            const int end = (r + 1 == N_NODES) ? N_EDGES
                                               : (offs[r + 1] + sh.P[(r + 1) >> 8]);
            float4 acc = make_float4(0.f, 0.f, 0.f, 0.f);
            int i = beg;
            for (; i + 8 <= end; i += 8) {
                int2 e[8];
#pragma unroll
                for (int j = 0; j < 8; ++j) e[j] = pe[i + j];
                ushort4 h[8];
#pragma unroll
                for (int j = 0; j < 8; ++j)
                    h[j] = *(const ushort4*)&Hb[((unsigned)e[j].x << 8) + lb];
#pragma unroll
                for (int j = 0; j < 8; ++j) {
                    const float v = __int_as_float(e[j].y);
                    acc.x += v * bf2f(h[j].x);
                    acc.y += v * bf2f(h[j].y);
                    acc.z += v * bf2f(h[j].z);
                    acc.w += v * bf2f(h[j].w);
                }
            }
            for (; i < end; ++i) {
                const int2 e0 = pe[i];
                const ushort4 h0 = *(const ushort4*)&Hb[((unsigned)e0.x << 8) + lb];
                const float v0 = __int_as_float(e0.y);
                acc.x += v0 * bf2f(h0.x);
                acc.y += v0 * bf2f(h0.y);
                acc.z += v0 * bf2f(h0.z);
                acc.w += v0 * bf2f(h0.w);
            }
            float4 o;
            o.x = acc.x + bb.x; o.y = acc.y + bb.y;
            o.z = acc.z + bb.z; o.w = acc.w + bb.w;
            *(float4*)&out[(size_t)r * DIM + lane * 4] = o;
        }
    }
}

// ---------------- launch ----------------
extern "C" void kernel_launch(void* const* d_in, const int* in_sizes, int n_in,
                              void* d_out, int out_size, void* d_ws, size_t ws_size,
                              hipStream_t stream) {
    const float* x        = (const float*)d_in[0];
    const int*   adj_rows = (const int*)d_in[1];
    const int*   adj_cols = (const int*)d_in[2];
    const float* adj_vals = (const float*)d_in[3];
    const float* W        = (const float*)d_in[4];
    const float* b        = (const float*)d_in[5];
    float*       out      = (float*)d_out;

    char* ws = (char*)d_ws;
    size_t off = 0;
    auto alloc = [&](size_t bytes) {
        void* p = ws + off;
        off = (off + bytes + 255) & ~(size_t)255;
        return p;
    };
    unsigned short* hiddenb = (unsigned short*)alloc((size_t)N_NODES * DIM * 2); // 25.6 MB
    int*            offs    = (int*)alloc((size_t)N_NODES * sizeof(int));
    int*            cntbar  = (int*)alloc((size_t)N_NODES * sizeof(int) + 64);   // cnt + bar (memset together)
    int*            bsum    = (int*)alloc(256 * sizeof(int));
    unsigned short* rank    = (unsigned short*)alloc((size_t)N_EDGES * 2);       // 1.6 MB
    int2*           pe      = (int2*)alloc((size_t)N_EDGES * sizeof(int2));      // 6.4 MB
    int*      cnt = cntbar;
    unsigned* bar = (unsigned*)(cntbar + N_NODES);

    // zero cnt + barrier counter (graph-capture legal)
    hipMemsetAsync(cntbar, 0, (size_t)N_NODES * sizeof(int) + 64, stream);

    fused<<<GRID, NT, 0, stream>>>(x, W, adj_rows, adj_cols, adj_vals, b,
                                   hiddenb, offs, cnt, bar, bsum, rank, pe, out);
}

// Round 9
// 246.735 us; speedup vs baseline: 1.3916x; 1.3916x over previous
//
#include <hip/hip_runtime.h>

#define N_NODES 50000
#define N_EDGES 800000
#define DIM     256
#define NSTRIPS 1563         // ceil(50000/32)
#define NBLK_NODES 196       // ceil(50000/256)
#define GEMM_BLOCKS 196      // ceil(1563/8)
#define PREP_BLOCKS 256
#define CNT_BLOCKS 3125      // 800000/256
#define HALF_ROWS 25000

typedef __attribute__((ext_vector_type(8))) short bf16x8;
typedef __attribute__((ext_vector_type(4))) float f32x4;

__device__ __forceinline__ unsigned short f2bf(float f) {
    unsigned u = __float_as_uint(f);
    unsigned r = (u + 0x7fffu + ((u >> 16) & 1u)) >> 16;
    return (unsigned short)r;
}
__device__ __forceinline__ float bf2f(unsigned short h) {
    return __uint_as_float((unsigned)h << 16);
}

// block-wide exclusive scan over 256 ints (wave64-based)
__device__ __forceinline__ int block_excl_scan_256(int v, int* wsum, int* total) {
    const int lane = threadIdx.x & 63;
    const int wave = threadIdx.x >> 6;
    int x = v;
#pragma unroll
    for (int off = 1; off < 64; off <<= 1) {
        const int y = __shfl_up(x, off, 64);
        if (lane >= off) x += y;
    }
    if (lane == 63) wsum[wave] = x;
    __syncthreads();
    if (threadIdx.x == 0) {
        int s = 0;
#pragma unroll
        for (int w = 0; w < 4; ++w) { const int t = wsum[w]; wsum[w] = s; s += t; }
        *total = s;
    }
    __syncthreads();
    return wsum[wave] + x - v;
}

// ---------------- K1: [blocks 0..255] W^T bf16  ||  [blocks 256..] count+rank ----------------
__global__ __launch_bounds__(256)
void prep_count(const float* __restrict__ W, unsigned short* __restrict__ Wt,
                const int* __restrict__ rows, int* __restrict__ cnt,
                unsigned short* __restrict__ rank) {
    const int bid = blockIdx.x;
    if (bid < PREP_BLOCKS) {
        const int n = bid, k = threadIdx.x;
        Wt[n * DIM + k] = f2bf(W[(size_t)k * DIM + n]);
        return;
    }
    const int e = (bid - PREP_BLOCKS) * 256 + threadIdx.x;
    if (e < N_EDGES)
        rank[e] = (unsigned short)atomicAdd(&cnt[rows[e]], 1);
}

// ---------------- K2: GEMM hidden_bf16 = bf16(x) @ bf16(W) via MFMA ----------------
__global__ __launch_bounds__(512, 2)
void gemm_mfma(const float* __restrict__ X, const unsigned short* __restrict__ Wt,
               unsigned short* __restrict__ Hb) {
    __shared__ unsigned short wl[DIM * DIM];   // 128 KB, [n][k] swizzled
    const int tid = threadIdx.x;
    {
        const uint4* src = (const uint4*)Wt;
#pragma unroll
        for (int i = 0; i < 16; ++i) {
            const int c   = i * 512 + tid;
            const int row = c >> 5;
            const int kb  = (c & 31) * 16;
            const int dst = row * 512 + (kb ^ ((row & 7) << 4));
            *(uint4*)((char*)wl + dst) = src[c];
        }
    }
    __syncthreads();

    const int wid   = tid >> 6;
    const int lane  = tid & 63;
    const int strip = blockIdx.x * 8 + wid;
    if (strip >= NSTRIPS) return;

    const int r0   = strip * 32;
    const int arow = lane & 15;
    const int kgrp = lane >> 4;
    const int ra = r0 + arow;
    const int rb = r0 + 16 + arow;
    const float* xa = X + (size_t)(ra < N_NODES ? ra : N_NODES - 1) * DIM + kgrp * 8;
    const float* xb = X + (size_t)(rb < N_NODES ? rb : N_NODES - 1) * DIM + kgrp * 8;

    f32x4 acc[2][16];
#pragma unroll
    for (int h = 0; h < 2; ++h)
#pragma unroll
        for (int nt = 0; nt < 16; ++nt) acc[h][nt] = f32x4{0.f, 0.f, 0.f, 0.f};

    const int swz = (arow & 7) << 4;
    float4 pa0 = *(const float4*)(xa);
    float4 pa1 = *(const float4*)(xa + 4);
    float4 pb0 = *(const float4*)(xb);
    float4 pb1 = *(const float4*)(xb + 4);

#pragma unroll
    for (int ks = 0; ks < 8; ++ks) {
        bf16x8 a0, a1;
        a0[0] = (short)f2bf(pa0.x); a0[1] = (short)f2bf(pa0.y);
        a0[2] = (short)f2bf(pa0.z); a0[3] = (short)f2bf(pa0.w);
        a0[4] = (short)f2bf(pa1.x); a0[5] = (short)f2bf(pa1.y);
        a0[6] = (short)f2bf(pa1.z); a0[7] = (short)f2bf(pa1.w);
        a1[0] = (short)f2bf(pb0.x); a1[1] = (short)f2bf(pb0.y);
        a1[2] = (short)f2bf(pb0.z); a1[3] = (short)f2bf(pb0.w);
        a1[4] = (short)f2bf(pb1.x); a1[5] = (short)f2bf(pb1.y);
        a1[6] = (short)f2bf(pb1.z); a1[7] = (short)f2bf(pb1.w);
        if (ks < 7) {
            pa0 = *(const float4*)(xa + (ks + 1) * 32);
            pa1 = *(const float4*)(xa + (ks + 1) * 32 + 4);
            pb0 = *(const float4*)(xb + (ks + 1) * 32);
            pb1 = *(const float4*)(xb + (ks + 1) * 32 + 4);
        }
        const int kb = ((ks * 32 + kgrp * 8) * 2) ^ swz;
#pragma unroll
        for (int nt = 0; nt < 16; ++nt) {
            const int n = nt * 16 + arow;
            const bf16x8 b = *(const bf16x8*)((const char*)wl + n * 512 + kb);
            acc[0][nt] = __builtin_amdgcn_mfma_f32_16x16x32_bf16(a0, b, acc[0][nt], 0, 0, 0);
            acc[1][nt] = __builtin_amdgcn_mfma_f32_16x16x32_bf16(a1, b, acc[1][nt], 0, 0, 0);
        }
    }
#pragma unroll
    for (int h = 0; h < 2; ++h) {
        const int crow0 = r0 + h * 16 + kgrp * 4;
#pragma unroll
        for (int nt = 0; nt < 16; ++nt) {
#pragma unroll
            for (int q = 0; q < 4; ++q) {
                const int r = crow0 + q;
                if (r < N_NODES)
                    Hb[(size_t)r * DIM + nt * 16 + arow] = f2bf(acc[h][nt][q]);
            }
        }
    }
}

// ---------------- K3: per-256-chunk exclusive scan; bsum[blk] = chunk total ----------------
__global__ __launch_bounds__(256)
void scan_blocks(const int* __restrict__ cnt, int* __restrict__ offs,
                 int* __restrict__ bsum) {
    __shared__ int wsum[4];
    __shared__ int total;
    const int i = blockIdx.x * 256 + threadIdx.x;
    const int v = (i < N_NODES) ? cnt[i] : 0;
    const int excl = block_excl_scan_256(v, wsum, &total);
    if (i < N_NODES) offs[i] = excl;
    if (threadIdx.x == 0) bsum[blockIdx.x] = total;
}

// ---------------- K4: fill dest-CSR (no atomics) + absolute-offset writeback ----------------
__global__ __launch_bounds__(256)
void fill_edges(const int* __restrict__ rows, const int* __restrict__ cols,
                const float* __restrict__ vals, const int* __restrict__ offs,
                const int* __restrict__ bsum, const unsigned short* __restrict__ rank,
                int2* __restrict__ pe, int* __restrict__ offs_abs) {
    __shared__ int wsum[4];
    __shared__ int total;
    __shared__ int P[256];
    {
        const int t = threadIdx.x;
        const int v = (t < NBLK_NODES) ? bsum[t] : 0;
        const int excl = block_excl_scan_256(v, wsum, &total);
        P[t] = excl;
    }
    __syncthreads();
    const int bid = blockIdx.x;
    // blocks 0..195 also publish absolute offsets for spmm
    if (bid < NBLK_NODES) {
        const int i = bid * 256 + threadIdx.x;
        if (i < N_NODES) offs_abs[i] = offs[i] + P[bid];
        if (bid == 0 && threadIdx.x == 0) offs_abs[N_NODES] = N_EDGES;
    }
    const int e = bid * 256 + threadIdx.x;
    if (e >= N_EDGES) return;
    const int r = rows[e];
    pe[offs[r] + P[r >> 8] + (int)rank[e]] = make_int2(cols[e], __float_as_int(vals[e]));
}

// ---------------- K5/K6: SpMM halves: out[r] = sum val * hidden[col] + b ----------------
__global__ __launch_bounds__(256)
void spmm(const unsigned short* __restrict__ Hb, const int* __restrict__ offs_abs,
          const int2* __restrict__ pe, const float* __restrict__ bias,
          float* __restrict__ out, int row_base) {
    const int row  = row_base + blockIdx.x * 4 + (threadIdx.x >> 6);
    const int lane = threadIdx.x & 63;
    const int beg = offs_abs[row];
    const int end = offs_abs[row + 1];
    const unsigned lb = (unsigned)lane * 4;
    float4 acc = make_float4(0.f, 0.f, 0.f, 0.f);
    int i = beg;
    for (; i + 8 <= end; i += 8) {
        int2 e[8];
#pragma unroll
        for (int j = 0; j < 8; ++j) e[j] = pe[i + j];
        ushort4 h[8];
#pragma unroll
        for (int j = 0; j < 8; ++j)
            h[j] = *(const ushort4*)&Hb[((unsigned)e[j].x << 8) + lb];
#pragma unroll
        for (int j = 0; j < 8; ++j) {
            const float v = __int_as_float(e[j].y);
            acc.x += v * bf2f(h[j].x);
            acc.y += v * bf2f(h[j].y);
            acc.z += v * bf2f(h[j].z);
            acc.w += v * bf2f(h[j].w);
        }
    }
    for (; i < end; ++i) {
        const int2 e0 = pe[i];
        const ushort4 h0 = *(const ushort4*)&Hb[((unsigned)e0.x << 8) + lb];
        const float v0 = __int_as_float(e0.y);
        acc.x += v0 * bf2f(h0.x);
        acc.y += v0 * bf2f(h0.y);
        acc.z += v0 * bf2f(h0.z);
        acc.w += v0 * bf2f(h0.w);
    }
    const float4 bb = *(const float4*)&bias[lane * 4];
    acc.x += bb.x; acc.y += bb.y; acc.z += bb.z; acc.w += bb.w;
    *(float4*)&out[(size_t)row * DIM + lane * 4] = acc;
}

// ---------------- launch ----------------
extern "C" void kernel_launch(void* const* d_in, const int* in_sizes, int n_in,
                              void* d_out, int out_size, void* d_ws, size_t ws_size,
                              hipStream_t stream) {
    const float* x        = (const float*)d_in[0];
    const int*   adj_rows = (const int*)d_in[1];
    const int*   adj_cols = (const int*)d_in[2];
    const float* adj_vals = (const float*)d_in[3];
    const float* W        = (const float*)d_in[4];
    const float* b        = (const float*)d_in[5];
    float*       out      = (float*)d_out;

    char* ws = (char*)d_ws;
    size_t off = 0;
    auto alloc = [&](size_t bytes) {
        void* p = ws + off;
        off = (off + bytes + 255) & ~(size_t)255;
        return p;
    };
    unsigned short* hiddenb  = (unsigned short*)alloc((size_t)N_NODES * DIM * 2); // 25.6 MB
    unsigned short* Wt       = (unsigned short*)alloc((size_t)DIM * DIM * 2);     // 128 KB
    int*            offs     = (int*)alloc((size_t)N_NODES * sizeof(int));
    int*            offs_abs = (int*)alloc((size_t)(N_NODES + 1) * sizeof(int));
    int*            cnt      = (int*)alloc((size_t)N_NODES * sizeof(int));
    int*            bsum     = (int*)alloc(256 * sizeof(int));
    unsigned short* rank     = (unsigned short*)alloc((size_t)N_EDGES * 2);       // 1.6 MB
    int2*           pe       = (int2*)alloc((size_t)N_EDGES * sizeof(int2));      // 6.4 MB

    // zero cnt
    hipMemsetAsync(cnt, 0, (size_t)N_NODES * sizeof(int), stream);

    // K1: W^T prep || count+rank (independent block ranges)
    prep_count<<<PREP_BLOCKS + CNT_BLOCKS, 256, 0, stream>>>(W, Wt, adj_rows, cnt, rank);

    // K2: GEMM (MFMA, LDS-resident W^T)
    gemm_mfma<<<GEMM_BLOCKS, 512, 0, stream>>>(x, Wt, hiddenb);

    // K3: per-chunk scan
    scan_blocks<<<NBLK_NODES, 256, 0, stream>>>(cnt, offs, bsum);

    // K4: fill dest-CSR + absolute offsets
    fill_edges<<<CNT_BLOCKS, 256, 0, stream>>>(
        adj_rows, adj_cols, adj_vals, offs, bsum, rank, pe, offs_abs);

    // K5/K6: SpMM halves (split so secondary kernels surface in top-5 profiling)
    spmm<<<HALF_ROWS / 4, 256, 0, stream>>>(hiddenb, offs_abs, pe, b, out, 0);
    spmm<<<HALF_ROWS / 4, 256, 0, stream>>>(hiddenb, offs_abs, pe, b, out, HALF_ROWS);
}